// Round 3
// baseline (248.462 us; speedup 1.0000x reference)
//
#include <hip/hip_runtime.h>

#define PP 10
#define FF 64
#define LL 2
#define BLOCK 64   // 1 wave per block: finest dispatch granularity, no barriers
#define EPT 4      // elements per thread: 4 independent dep-chains per weight

// ---- workspace layout (float offsets) ----
#define WS_P2   0      // p2[10]
#define WS_M1   16     // M1[L][10][10] fused diag(ln1g)@Wv@Wo
#define WS_C1   216    // c1[L][10] fused attn bias
#define WS_W1T  240    // W1t[L][64][10] = ln2g[j]*W1[j][f], transposed
#define WS_B1F  1520   // b1f[L][64] = b1 + ln2b @ W1

__device__ __forceinline__ float fast_sigmoid(float z) {
    return __builtin_amdgcn_rcpf(1.0f + __expf(-z));
}

// gelu(x) = x * sigmoid(2c(x+0.044715x^3)), c = sqrt(2/pi)
__device__ __forceinline__ float gelu_fast(float x) {
    float x3 = x * x * x;
    float z2 = 1.5957691216057308f * x + 0.0713548162726f * x3;
    return x * __builtin_amdgcn_rcpf(1.0f + __expf(-z2));
}

__global__ __launch_bounds__(256) void prep_kernel(
    const float* __restrict__ protos,
    const float* __restrict__ Wv, const float* __restrict__ bv,
    const float* __restrict__ Wo, const float* __restrict__ bo,
    const float* __restrict__ ln1g, const float* __restrict__ ln1b,
    const float* __restrict__ ln2g, const float* __restrict__ ln2b,
    const float* __restrict__ W1, const float* __restrict__ b1,
    float* __restrict__ ws)
{
    const int t = threadIdx.x;
    if (t < PP) {
        float s = 0.0f;
        for (int k = 0; k < 8; ++k) { float v = protos[t * 8 + k]; s += v * v; }
        ws[WS_P2 + t] = s;
    }
    for (int idx = t; idx < LL * PP * PP; idx += 256) {
        int l = idx / (PP * PP);
        int r = idx % (PP * PP);
        int j = r / PP, o = r % PP;
        float s = 0.0f;
        for (int m = 0; m < PP; ++m)
            s += Wv[l * PP * PP + j * PP + m] * Wo[l * PP * PP + m * PP + o];
        ws[WS_M1 + idx] = ln1g[l * PP + j] * s;
    }
    for (int idx = t; idx < LL * PP; idx += 256) {
        int l = idx / PP, o = idx % PP;
        float s = bo[l * PP + o];
        for (int m = 0; m < PP; ++m) s += bv[l * PP + m] * Wo[l * PP * PP + m * PP + o];
        for (int j = 0; j < PP; ++j) {
            float wv_wo = 0.0f;
            for (int m = 0; m < PP; ++m)
                wv_wo += Wv[l * PP * PP + j * PP + m] * Wo[l * PP * PP + m * PP + o];
            s += ln1b[l * PP + j] * wv_wo;
        }
        ws[WS_C1 + idx] = s;
    }
    for (int idx = t; idx < LL * FF * PP; idx += 256) {
        int l = idx / (FF * PP);
        int r = idx % (FF * PP);
        int f = r / PP, j = r % PP;
        ws[WS_W1T + idx] = ln2g[l * PP + j] * W1[l * PP * FF + j * FF + f];
    }
    for (int idx = t; idx < LL * FF; idx += 256) {
        int l = idx / FF, f = idx % FF;
        float s = b1[l * FF + f];
        for (int j = 0; j < PP; ++j) s += ln2b[l * PP + j] * W1[l * PP * FF + j * FF + f];
        ws[WS_B1F + idx] = s;
    }
}

__global__ __launch_bounds__(BLOCK) void hqcnn_kernel(
    const float* __restrict__ x,       // B x 8
    const float* __restrict__ protos,  // PP x 8
    const float* __restrict__ W2,      // LL x FF x PP
    const float* __restrict__ b2,      // LL x PP
    const float* __restrict__ Wc,      // PP
    const float* __restrict__ bc,      // 1
    const float* __restrict__ ws,      // fused weights (uniform -> s_load)
    float* __restrict__ out, int B)
{
    const int t = threadIdx.x;
    const int base = blockIdx.x * (BLOCK * EPT) + t;

    int idx[EPT];
    bool valid[EPT];
#pragma unroll
    for (int e = 0; e < EPT; ++e) {
        int i = base + e * BLOCK;
        valid[e] = (i < B);
        idx[e] = valid[e] ? i : (B - 1);
    }

    // ---- load x (coalesced float4 pairs per element) ----
    float xv[EPT][8];
#pragma unroll
    for (int e = 0; e < EPT; ++e) {
        const float4 a = ((const float4*)x)[idx[e] * 2];
        const float4 b = ((const float4*)x)[idx[e] * 2 + 1];
        xv[e][0]=a.x; xv[e][1]=a.y; xv[e][2]=a.z; xv[e][3]=a.w;
        xv[e][4]=b.x; xv[e][5]=b.y; xv[e][6]=b.z; xv[e][7]=b.w;
    }

    // ---- kernel features: seq[p] = exp(-(x2 + p2 - 2 x.proto)) ----
    float x2[EPT];
#pragma unroll
    for (int e = 0; e < EPT; ++e) {
        float s = 0.0f;
#pragma unroll
        for (int k = 0; k < 8; ++k) s += xv[e][k] * xv[e][k];
        x2[e] = s;
    }
    float seq[EPT][PP];
#pragma unroll
    for (int p = 0; p < PP; ++p) {
        float p2 = ws[WS_P2 + p];
#pragma unroll
        for (int e = 0; e < EPT; ++e) {
            float dot = 0.0f;
#pragma unroll
            for (int k = 0; k < 8; ++k) dot += xv[e][k] * protos[p * 8 + k];
            seq[e][p] = __expf(-(x2[e] + p2 - 2.0f * dot));
        }
    }

    // ---- 2 transformer layers (seq_len==1 -> attn == v; all fused) ----
#pragma unroll
    for (int l = 0; l < LL; ++l) {
        float y[EPT][PP];
        // LN1 (standardize; affine folded into M1/c1)
#pragma unroll
        for (int e = 0; e < EPT; ++e) {
            float mu = 0.0f;
#pragma unroll
            for (int j = 0; j < PP; ++j) mu += seq[e][j];
            mu *= 0.1f;
            float var = 0.0f;
#pragma unroll
            for (int j = 0; j < PP; ++j) { float d = seq[e][j] - mu; var += d * d; }
            var *= 0.1f;
            float rs = __builtin_amdgcn_rsqf(var + 1e-5f);
            float mrs = -mu * rs;
#pragma unroll
            for (int j = 0; j < PP; ++j) y[e][j] = seq[e][j] * rs + mrs;
        }
        // fused attention: seq += y @ M1 + c1
#pragma unroll
        for (int o = 0; o < PP; ++o) {
            float c = ws[WS_C1 + l * PP + o];
            float a[EPT];
#pragma unroll
            for (int e = 0; e < EPT; ++e) a[e] = c;
#pragma unroll
            for (int j = 0; j < PP; ++j) {
                float w = ws[WS_M1 + l * PP * PP + j * PP + o];
#pragma unroll
                for (int e = 0; e < EPT; ++e) a[e] += y[e][j] * w;
            }
#pragma unroll
            for (int e = 0; e < EPT; ++e) seq[e][o] += a[e];
        }
        // LN2 (standardize; affine folded into W1t/b1f)
#pragma unroll
        for (int e = 0; e < EPT; ++e) {
            float mu = 0.0f;
#pragma unroll
            for (int j = 0; j < PP; ++j) mu += seq[e][j];
            mu *= 0.1f;
            float var = 0.0f;
#pragma unroll
            for (int j = 0; j < PP; ++j) { float d = seq[e][j] - mu; var += d * d; }
            var *= 0.1f;
            float rs = __builtin_amdgcn_rsqf(var + 1e-5f);
            float mrs = -mu * rs;
#pragma unroll
            for (int j = 0; j < PP; ++j) y[e][j] = seq[e][j] * rs + mrs;
        }
        // FFN: seq += gelu(y @ W1t^T + b1f) @ W2 + b2
        float acc[EPT][PP];
#pragma unroll
        for (int o = 0; o < PP; ++o) {
            float b = b2[l * PP + o];
#pragma unroll
            for (int e = 0; e < EPT; ++e) acc[e][o] = b;
        }
#pragma unroll 2
        for (int f = 0; f < FF; ++f) {
            float bb = ws[WS_B1F + l * FF + f];
            float tt[EPT];
#pragma unroll
            for (int e = 0; e < EPT; ++e) tt[e] = bb;
#pragma unroll
            for (int j = 0; j < PP; ++j) {
                float w = ws[WS_W1T + l * FF * PP + f * PP + j];
#pragma unroll
                for (int e = 0; e < EPT; ++e) tt[e] += y[e][j] * w;
            }
            float u[EPT];
#pragma unroll
            for (int e = 0; e < EPT; ++e) u[e] = gelu_fast(tt[e]);
#pragma unroll
            for (int o = 0; o < PP; ++o) {
                float w = W2[l * FF * PP + f * PP + o];
#pragma unroll
                for (int e = 0; e < EPT; ++e) acc[e][o] += u[e] * w;
            }
        }
#pragma unroll
        for (int o = 0; o < PP; ++o) {
#pragma unroll
            for (int e = 0; e < EPT; ++e) seq[e][o] += acc[e][o];
        }
    }

    // ---- head + sigmoid ----
    float bcs = bc[0];
    float z[EPT];
#pragma unroll
    for (int e = 0; e < EPT; ++e) z[e] = bcs;
#pragma unroll
    for (int o = 0; o < PP; ++o) {
        float w = Wc[o];
#pragma unroll
        for (int e = 0; e < EPT; ++e) z[e] += seq[e][o] * w;
    }
#pragma unroll
    for (int e = 0; e < EPT; ++e) {
        if (valid[e]) out[base + e * BLOCK] = fast_sigmoid(z[e]);
    }
}

extern "C" void kernel_launch(void* const* d_in, const int* in_sizes, int n_in,
                              void* d_out, int out_size, void* d_ws, size_t ws_size,
                              hipStream_t stream) {
    const float* x      = (const float*)d_in[0];
    const float* protos = (const float*)d_in[1];
    // d_in[2..5] = Wq,bq,Wk,bk — dead (seq_len==1 => softmax==1 => o==v)
    const float* Wv   = (const float*)d_in[6];
    const float* bv   = (const float*)d_in[7];
    const float* Wo   = (const float*)d_in[8];
    const float* bo   = (const float*)d_in[9];
    const float* ln1g = (const float*)d_in[10];
    const float* ln1b = (const float*)d_in[11];
    const float* ln2g = (const float*)d_in[12];
    const float* ln2b = (const float*)d_in[13];
    const float* W1   = (const float*)d_in[14];
    const float* b1   = (const float*)d_in[15];
    const float* W2   = (const float*)d_in[16];
    const float* b2   = (const float*)d_in[17];
    const float* Wc   = (const float*)d_in[18];
    const float* bc   = (const float*)d_in[19];
    float* out = (float*)d_out;
    float* ws  = (float*)d_ws;

    prep_kernel<<<1, 256, 0, stream>>>(protos, Wv, bv, Wo, bo,
                                       ln1g, ln1b, ln2g, ln2b, W1, b1, ws);

    const int B = in_sizes[0] / 8;
    const int grid = (B + BLOCK * EPT - 1) / (BLOCK * EPT);
    hqcnn_kernel<<<grid, BLOCK, 0, stream>>>(x, protos, W2, b2, Wc, bc, ws, out, B);
}